// Round 4
// baseline (354.387 us; speedup 1.0000x reference)
//
#include <hip/hip_runtime.h>
#include <math.h>

#define B_ 8
#define T_ 64
#define N_ 196
#define D_ 768
#define K_ 8
#define FEAT 40
#define EPSF 1e-6f

constexpr int ROWS = B_ * T_ * N_;                 // 100352
constexpr long long HSIZE = (long long)ROWS * D_;  // 77070336

typedef float v4f __attribute__((ext_vector_type(4)));

__device__ __forceinline__ float wredux(float v) {
#pragma unroll
    for (int off = 32; off > 0; off >>= 1)
        v += __shfl_xor(v, off, 64);
    return v;
}

// W = softplus(W_raw) -> d_out tail;  beta_s = sigmoid(beta) -> ws
__global__ __launch_bounds__(256) void k_wsp(const float* __restrict__ wraw,
                                             const float* __restrict__ beta,
                                             float* __restrict__ wout,
                                             float* __restrict__ beta_s) {
    int i = blockIdx.x * blockDim.x + threadIdx.x;
    if (i < FEAT * D_) {
        float xw = wraw[i];
        wout[i] = fmaxf(xw, 0.0f) + log1pf(expf(-fabsf(xw)));
    }
    if (i < D_) beta_s[i] = 1.0f / (1.0f + expf(-beta[i]));
}

// Fused: one block per (b,n); 512 threads = 8 waves.
// Thread (wave w, lane l) holds x[t=l][d in w*96 .. w*96+96) as 24 v4f regs.
// x read from HBM exactly once; h written from the same registers.
__global__ __launch_bounds__(512) void k_fused(const float* __restrict__ x,
                                               const float* __restrict__ mask,
                                               const float* __restrict__ pw,
                                               const float* __restrict__ wsp,
                                               const float* __restrict__ beta_s,
                                               float* __restrict__ h) {
    __shared__ float uld[K_ * D_];        // 24 KB: proj_W
    __shared__ float vpart[8][K_][64];    // 16 KB: cross-wave dot partials
    __shared__ float sf[FEAT];            // feats
    __shared__ float ylds[D_];            // beta_s * y

    const int tid  = threadIdx.x;
    const int lane = tid & 63;
    const int w    = tid >> 6;
    const int bn   = blockIdx.x;
    const int b    = bn / N_;
    const int n    = bn - b * N_;

    // stage proj_W into LDS (1536 f4, coalesced: 3 f4/thread)
    {
        const v4f* p4 = (const v4f*)pw;
        v4f* u4w = (v4f*)uld;
#pragma unroll
        for (int i = 0; i < 3; i++)
            u4w[tid + 512 * i] = p4[tid + 512 * i];
    }

    // x loads: row t=lane, f4 cols w*24 .. w*24+23 (per-thread sequential)
    const size_t rowbase = ((size_t)(b * T_ + lane) * N_ + n) * (D_ / 4);
    const v4f* x4 = (const v4f*)x;
    v4f xr[24];
#pragma unroll
    for (int i = 0; i < 24; i++)
        xr[i] = x4[rowbase + w * 24 + i];

    const float m = mask[(b * T_ + lane) * N_ + n];

    __syncthreads();   // uld ready

    // dots: vpart[w][k][lane] = dot(xr, U[k][w-slice])  (U broadcast from LDS)
    const v4f* u4 = (const v4f*)uld;
#pragma unroll
    for (int k = 0; k < K_; k++) {
        float a = 0.f;
#pragma unroll
        for (int i = 0; i < 24; i++) {
            v4f uu = u4[k * 192 + w * 24 + i];
            a += xr[i].x * uu.x + xr[i].y * uu.y + xr[i].z * uu.z + xr[i].w * uu.w;
        }
        vpart[w][k][lane] = a;
    }
    __syncthreads();

    // phase 3: wave w owns k=w; lane = t. rms -> tanh bound -> DCT/mean/rms.
    {
        const int k = w;
        float v = 0.f;
#pragma unroll
        for (int ww = 0; ww < 8; ww++) v += vpart[ww][k][lane];
        v *= m;
        float s2  = wredux(v * v);
        float rms = sqrtf(s2 * (1.0f / T_) + EPSF);
        float vb  = 2.5f * tanhf(v / (rms + EPSF));
        const float PI = 3.14159265358979323846f;
        float ph = PI * ((float)lane + 0.5f) / (float)T_;
        float c1 = cosf(ph), c2 = cosf(2.0f * ph);
        float n1 = wredux(c1 * c1), n2 = wredux(c2 * c2);
        float S1 = wredux(vb), Sc1 = wredux(vb * c1);
        float Sc2 = wredux(vb * c2), Sq = wredux(vb * vb);
        if (lane == 0) {
            float* o = sf + k * 5;
            o[0] = S1 / (8.0f + EPSF);
            o[1] = Sc1 / (sqrtf(n1) + EPSF);
            o[2] = Sc2 / (sqrtf(n2) + EPSF);
            o[3] = S1 * (1.0f / T_);
            o[4] = sqrtf(Sq * (1.0f / T_) + EPSF);
        }
    }
    __syncthreads();

    // phase 4: ylds[d] = beta_s[d] * sum_f sf[f]*wsp[f][d]   (wsp is L2-hot)
    for (int d = tid; d < D_; d += 512) {
        float a = 0.f;
#pragma unroll
        for (int f = 0; f < FEAT; f++)
            a += sf[f] * wsp[f * D_ + d];
        ylds[d] = a * beta_s[d];
    }
    __syncthreads();

    // phase 5: h = x + m * ylds   (x still in registers)
    v4f* h4 = (v4f*)h;
    const v4f* y4 = (const v4f*)ylds;
#pragma unroll
    for (int i = 0; i < 24; i++) {
        v4f r = xr[i] + m * y4[w * 24 + i];
        h4[rowbase + w * 24 + i] = r;
    }
}

extern "C" void kernel_launch(void* const* d_in, const int* in_sizes, int n_in,
                              void* d_out, int out_size, void* d_ws, size_t ws_size,
                              hipStream_t stream) {
    const float* x    = (const float*)d_in[0];
    const float* mask = (const float*)d_in[1];
    const float* pw   = (const float*)d_in[2];
    const float* wraw = (const float*)d_in[3];
    const float* beta = (const float*)d_in[4];

    float* h    = (float*)d_out;
    float* wout = h + HSIZE;

    float* beta_s = (float*)d_ws;   // [768]

    hipLaunchKernelGGL(k_wsp, dim3((FEAT * D_ + 255) / 256), dim3(256), 0, stream,
                       wraw, beta, wout, beta_s);
    hipLaunchKernelGGL(k_fused, dim3(B_ * N_), dim3(512), 0, stream,
                       x, mask, pw, wout, beta_s, h);
}

// Round 5
// 302.937 us; speedup vs baseline: 1.1698x; 1.1698x over previous
//
#include <hip/hip_runtime.h>
#include <math.h>

#define B_ 8
#define T_ 64
#define N_ 196
#define D_ 768
#define K_ 8
#define FEAT 40
#define EPSF 1e-6f

constexpr int ROWS = B_ * T_ * N_;                 // 100352
constexpr long long HSIZE = (long long)ROWS * D_;  // 77070336
constexpr int QPR = D_ / 4;                        // 192 float4 per row

typedef float v4f __attribute__((ext_vector_type(4)));

__device__ __forceinline__ float wredux(float v) {
#pragma unroll
    for (int off = 32; off > 0; off >>= 1)
        v += __shfl_xor(v, off, 64);
    return v;
}

__device__ __forceinline__ float dot4(v4f a, v4f b) {
    return a.x * b.x + a.y * b.y + a.z * b.z + a.w * b.w;
}

// W = softplus(W_raw) -> d_out tail;  beta_s = sigmoid(beta) -> ws
__global__ __launch_bounds__(256) void k_wsp(const float* __restrict__ wraw,
                                             const float* __restrict__ beta,
                                             float* __restrict__ wout,
                                             float* __restrict__ beta_s) {
    int i = blockIdx.x * blockDim.x + threadIdx.x;
    if (i < FEAT * D_) {
        float xw = wraw[i];
        wout[i] = fmaxf(xw, 0.0f) + log1pf(expf(-fabsf(xw)));
    }
    if (i < D_) beta_s[i] = 1.0f / (1.0f + expf(-beta[i]));
}

// Fused: one block per (b,n); 1024 threads = 16 waves, wave w owns rows
// t = 4w..4w+3. Each row loaded wave-coalesced (lane-contiguous float4),
// x kept in 12 v4f regs; proj_W broadcast from LDS; h written from regs.
__global__ __launch_bounds__(1024) void k_fused(const float* __restrict__ x,
                                                const float* __restrict__ mask,
                                                const float* __restrict__ pw,
                                                const float* __restrict__ wsp,
                                                const float* __restrict__ beta_s,
                                                float* __restrict__ h) {
    __shared__ float uld[K_ * D_];        // 24 KB proj_W
    __shared__ float vpart[K_][T_];       // 2 KB   v[k][t]
    __shared__ float sf[FEAT];
    __shared__ float ylds[D_];            // 3 KB   beta_s * y
    __shared__ float smask[T_];

    const int tid  = threadIdx.x;
    const int lane = tid & 63;
    const int w    = tid >> 6;
    const int bn   = blockIdx.x;
    const int b    = bn / N_;
    const int n    = bn - b * N_;

    // stage proj_W (1536 v4f) + mask column
    {
        const v4f* p4 = (const v4f*)pw;
        v4f* u4w = (v4f*)uld;
        if (tid < 768) {
            u4w[tid]       = p4[tid];
            u4w[tid + 768] = p4[tid + 768];
        }
        if (tid < T_) smask[tid] = mask[(b * T_ + tid) * N_ + n];
    }

    // x loads: wave w, rows t=4w+i, lane-contiguous float4 (coalesced 1KB)
    const v4f* x4 = (const v4f*)x;
    unsigned qb[4];
    v4f xr[4][3];
#pragma unroll
    for (int i = 0; i < 4; i++) {
        int t = w * 4 + i;
        qb[i] = (unsigned)(((b * T_ + t) * N_ + n)) * QPR;
#pragma unroll
        for (int c = 0; c < 3; c++)
            xr[i][c] = x4[qb[i] + c * 64 + lane];
    }

    __syncthreads();   // uld, smask ready

    // dots: k-outer so U slice (3 v4f) is loaded once per k
    const v4f* u4 = (const v4f*)uld;
    float acc[4][8];
#pragma unroll
    for (int k = 0; k < K_; k++) {
        v4f u0 = u4[k * 192 + lane];
        v4f u1 = u4[k * 192 + 64 + lane];
        v4f u2 = u4[k * 192 + 128 + lane];
#pragma unroll
        for (int i = 0; i < 4; i++)
            acc[i][k] = dot4(xr[i][0], u0) + dot4(xr[i][1], u1) + dot4(xr[i][2], u2);
    }
#pragma unroll
    for (int i = 0; i < 4; i++) {
#pragma unroll
        for (int k = 0; k < K_; k++)
            acc[i][k] = wredux(acc[i][k]);
        float val = acc[i][0];
#pragma unroll
        for (int k = 1; k < K_; k++)
            val = (lane == k) ? acc[i][k] : val;
        if (lane < K_) vpart[lane][w * 4 + i] = val;
    }
    __syncthreads();

    // stats: wave w<8 owns k=w; lane = t  (validated math)
    if (w < K_) {
        float v = vpart[w][lane] * smask[lane];
        float s2  = wredux(v * v);
        float rms = sqrtf(s2 * (1.0f / T_) + EPSF);
        float vb  = 2.5f * tanhf(v / (rms + EPSF));
        const float PI = 3.14159265358979323846f;
        float ph = PI * ((float)lane + 0.5f) / (float)T_;
        float c1 = cosf(ph), c2 = cosf(2.0f * ph);
        float n1 = wredux(c1 * c1), n2 = wredux(c2 * c2);
        float S1 = wredux(vb), Sc1 = wredux(vb * c1);
        float Sc2 = wredux(vb * c2), Sq = wredux(vb * vb);
        if (lane == 0) {
            float* o = sf + w * 5;
            o[0] = S1 / (8.0f + EPSF);
            o[1] = Sc1 / (sqrtf(n1) + EPSF);
            o[2] = Sc2 / (sqrtf(n2) + EPSF);
            o[3] = S1 * (1.0f / T_);
            o[4] = sqrtf(Sq * (1.0f / T_) + EPSF);
        }
    }
    __syncthreads();

    // tiny GEMM: ylds[d] = beta_s[d] * sum_f sf[f] * wsp[f][d]
    if (tid < D_) {
        float a0 = 0.f, a1 = 0.f;
#pragma unroll
        for (int f = 0; f < FEAT; f += 2) {
            a0 += sf[f]     * wsp[f * D_ + tid];
            a1 += sf[f + 1] * wsp[(f + 1) * D_ + tid];
        }
        ylds[tid] = (a0 + a1) * beta_s[tid];
    }
    __syncthreads();

    // h = x + m * ylds, written from registers, nontemporal
    const v4f* y4 = (const v4f*)ylds;
    v4f y0 = y4[lane], y1 = y4[64 + lane], y2 = y4[128 + lane];
    v4f* h4 = (v4f*)h;
#pragma unroll
    for (int i = 0; i < 4; i++) {
        float m = smask[w * 4 + i];
        __builtin_nontemporal_store(xr[i][0] + m * y0, h4 + qb[i] + lane);
        __builtin_nontemporal_store(xr[i][1] + m * y1, h4 + qb[i] + 64 + lane);
        __builtin_nontemporal_store(xr[i][2] + m * y2, h4 + qb[i] + 128 + lane);
    }
}

extern "C" void kernel_launch(void* const* d_in, const int* in_sizes, int n_in,
                              void* d_out, int out_size, void* d_ws, size_t ws_size,
                              hipStream_t stream) {
    const float* x    = (const float*)d_in[0];
    const float* mask = (const float*)d_in[1];
    const float* pw   = (const float*)d_in[2];
    const float* wraw = (const float*)d_in[3];
    const float* beta = (const float*)d_in[4];

    float* h    = (float*)d_out;
    float* wout = h + HSIZE;
    float* beta_s = (float*)d_ws;   // [768]

    hipLaunchKernelGGL(k_wsp, dim3((FEAT * D_ + 255) / 256), dim3(256), 0, stream,
                       wraw, beta, wout, beta_s);
    hipLaunchKernelGGL(k_fused, dim3(B_ * N_), dim3(1024), 0, stream,
                       x, mask, pw, wout, beta_s, h);
}